// Round 7
// baseline (600.284 us; speedup 1.0000x reference)
//
#include <hip/hip_runtime.h>
#include <math.h>

#define SB 8192
#define NB 32
#define WC 64
#define NM 16
#define NKC 32   // 2*NM (cos,sin interleaved)
#define NP 24
#define NSC 16   // K-split slices per batch for k_dft
#define LP 132   // padded Tt row length
#define HP 68    // padded hS row length (64 + 4)

// h layout is TRANSPOSED: h2[b][s][ch] (ch contiguous, 256B per s-point)
// ws layout (float offsets):
//   h2   : 0         (B*S*W = 16777216)
//   T    : 16777216  (S*32  = 262144)
//   xf   : 17039360  (B*W*32 = 65536)
//   of   : 17104896  (B*W*32 = 65536)
//   icaT : 17170432  (128*24 = 3072)
// k_dft partials (32*16*2048 = 1M floats) live in the tc output region (dead until k_final).

__global__ __launch_bounds__(256) void k_table(float* __restrict__ T) {
    int s = blockIdx.x * 256 + threadIdx.x;   // exactly 8192 threads
    float* row = T + (size_t)s * NKC;
    #pragma unroll
    for (int k = 0; k < NM; ++k) {
        int m = (k * s) & (SB - 1);           // exact phase mod S
        double ang = (double)m * (6.283185307179586476925286766559 / (double)SB);
        row[2 * k]     = (float)cos(ang);
        row[2 * k + 1] = (float)sin(ang);
    }
}

// icaT[c][p] = fc2_w[0][c] * ica_w[p][c]
__global__ __launch_bounds__(256) void k_prep(const float* __restrict__ ica_w,
                                              const float* __restrict__ fc2_w,
                                              float* __restrict__ icaT) {
    int tid = blockIdx.x * 256 + threadIdx.x;   // exactly 3072
    int c = tid / NP;
    int p = tid - c * NP;
    icaT[c * NP + p] = ica_w[p * 128 + c] * fc2_w[c];
}

// lift: h2[b][s][w] = x[b][s][0]*fc0_w[w][0] + x[b][s][1]*fc0_w[w][1] + fc0_b[w]
// 16 dense float4 stores per thread (256B contiguous).
__global__ __launch_bounds__(256) void k_lift(const float* __restrict__ x,
                                              const float* __restrict__ fc0_w,
                                              const float* __restrict__ fc0_b,
                                              float* __restrict__ h2) {
    int b = blockIdx.y;
    int s = blockIdx.x * 256 + threadIdx.x;
    float2 xv = ((const float2*)x)[(size_t)b * SB + s];
    float4* dst = (float4*)(h2 + ((size_t)b * SB + s) * WC);
    #pragma unroll
    for (int q = 0; q < 16; ++q) {
        float4 v;
        v.x = fmaf(xv.x, fc0_w[2*(4*q+0)], fmaf(xv.y, fc0_w[2*(4*q+0)+1], fc0_b[4*q+0]));
        v.y = fmaf(xv.x, fc0_w[2*(4*q+1)], fmaf(xv.y, fc0_w[2*(4*q+1)+1], fc0_b[4*q+1]));
        v.z = fmaf(xv.x, fc0_w[2*(4*q+2)], fmaf(xv.y, fc0_w[2*(4*q+2)+1], fc0_b[4*q+2]));
        v.w = fmaf(xv.x, fc0_w[2*(4*q+3)], fmaf(xv.y, fc0_w[2*(4*q+3)+1], fc0_b[4*q+3]));
        dst[q] = v;
    }
}

// forward DFT as LDS-staged GEMM from h2[b][s][ch].
// Block = (b, sc): K-slice of 512 s. Per 128-s subtile: stage hS[128][64]
// (contiguous 32KB block copy) + T^t[32][128]; thread (g=t>>4, j=t&15) owns
// channels g*4..+4, modes j and j+16. h-reads are 16-lane broadcast groups.
__global__ __launch_bounds__(256) void k_dft(const float* __restrict__ h2,
                                             const float* __restrict__ T,
                                             float* __restrict__ xfp) {
    __shared__ float hS[128][HP];  // 34816 B
    __shared__ float Tt[32][LP];   // 16896 B
    int blk = blockIdx.x;          // b*NSC + sc
    int b  = blk >> 4;
    int sc = blk & (NSC - 1);
    int t  = threadIdx.x;
    int g = t >> 4, j = t & 15;

    float acc[4][2];
    #pragma unroll
    for (int i = 0; i < 4; ++i) { acc[i][0] = 0.f; acc[i][1] = 0.f; }

    int sl   = t >> 1;             // Tt staging role
    int jj0  = (t & 1) * 16;

    for (int st = 0; st < 4; ++st) {
        int s_base = sc * 512 + st * 128;

        // stage hS: 128 s x 64 ch = contiguous 8192 floats, fully coalesced
        const float4* src4 = (const float4*)(h2 + ((size_t)b * SB + s_base) * WC);
        #pragma unroll
        for (int r = 0; r < 8; ++r) {
            int idx = t + r * 256;           // float4 index
            float4 v = src4[idx];
            int ss = idx >> 4, cc4 = (idx & 15) * 4;
            *(float4*)&hS[ss][cc4] = v;
        }
        // stage T^t[32][128]
        {
            const float4* src = (const float4*)(T + (size_t)(s_base + sl) * NKC + jj0);
            float4 a = src[0], c4 = src[1], d = src[2], e = src[3];
            Tt[jj0 +  0][sl] = a.x;  Tt[jj0 +  1][sl] = a.y;
            Tt[jj0 +  2][sl] = a.z;  Tt[jj0 +  3][sl] = a.w;
            Tt[jj0 +  4][sl] = c4.x; Tt[jj0 +  5][sl] = c4.y;
            Tt[jj0 +  6][sl] = c4.z; Tt[jj0 +  7][sl] = c4.w;
            Tt[jj0 +  8][sl] = d.x;  Tt[jj0 +  9][sl] = d.y;
            Tt[jj0 + 10][sl] = d.z;  Tt[jj0 + 11][sl] = d.w;
            Tt[jj0 + 12][sl] = e.x;  Tt[jj0 + 13][sl] = e.y;
            Tt[jj0 + 14][sl] = e.z;  Tt[jj0 + 15][sl] = e.w;
        }
        __syncthreads();

        #pragma unroll 4
        for (int step = 0; step < 32; ++step) {
            int s4 = step * 4;
            float4 ta = *(const float4*)&Tt[j][s4];
            float4 tb = *(const float4*)&Tt[j + 16][s4];
            float4 h0 = *(const float4*)&hS[s4 + 0][g * 4];
            float4 h1 = *(const float4*)&hS[s4 + 1][g * 4];
            float4 h2v = *(const float4*)&hS[s4 + 2][g * 4];
            float4 h3 = *(const float4*)&hS[s4 + 3][g * 4];
            acc[0][0] = fmaf(h0.x, ta.x, fmaf(h1.x, ta.y, fmaf(h2v.x, ta.z, fmaf(h3.x, ta.w, acc[0][0]))));
            acc[0][1] = fmaf(h0.x, tb.x, fmaf(h1.x, tb.y, fmaf(h2v.x, tb.z, fmaf(h3.x, tb.w, acc[0][1]))));
            acc[1][0] = fmaf(h0.y, ta.x, fmaf(h1.y, ta.y, fmaf(h2v.y, ta.z, fmaf(h3.y, ta.w, acc[1][0]))));
            acc[1][1] = fmaf(h0.y, tb.x, fmaf(h1.y, tb.y, fmaf(h2v.y, tb.z, fmaf(h3.y, tb.w, acc[1][1]))));
            acc[2][0] = fmaf(h0.z, ta.x, fmaf(h1.z, ta.y, fmaf(h2v.z, ta.z, fmaf(h3.z, ta.w, acc[2][0]))));
            acc[2][1] = fmaf(h0.z, tb.x, fmaf(h1.z, tb.y, fmaf(h2v.z, tb.z, fmaf(h3.z, tb.w, acc[2][1]))));
            acc[3][0] = fmaf(h0.w, ta.x, fmaf(h1.w, ta.y, fmaf(h2v.w, ta.z, fmaf(h3.w, ta.w, acc[3][0]))));
            acc[3][1] = fmaf(h0.w, tb.x, fmaf(h1.w, tb.y, fmaf(h2v.w, tb.z, fmaf(h3.w, tb.w, acc[3][1]))));
        }
        __syncthreads();
    }

    float* dst = xfp + ((size_t)(sc * NB + b)) * 2048;
    #pragma unroll
    for (int i = 0; i < 4; ++i) {
        dst[(g * 4 + i) * 32 + j]      = acc[i][0];
        dst[(g * 4 + i) * 32 + j + 16] = acc[i][1];
    }
}

// reduce K-split partials
__global__ __launch_bounds__(256) void k_red(const float* __restrict__ xfp,
                                             float* __restrict__ xf) {
    int idx = blockIdx.x * 256 + threadIdx.x;   // exactly 65536
    int b = idx >> 11;
    int r = idx & 2047;
    float s = 0.f;
    #pragma unroll
    for (int sc = 0; sc < NSC; ++sc)
        s += xfp[((size_t)(sc * NB + b)) * 2048 + r];
    xf[idx] = s;
}

// mode mix: of[b][o][2k] = alpha*Re, of[b][o][2k+1] = -alpha*Im
__global__ __launch_bounds__(256) void k_mix(const float* __restrict__ xf,
                                             const float* __restrict__ wr,
                                             const float* __restrict__ wi,
                                             float* __restrict__ of) {
    int tid = blockIdx.x * 256 + threadIdx.x;   // exactly 32768
    int k = tid & 15;
    int o = (tid >> 4) & 63;
    int b = tid >> 10;
    float orr = 0.f, oii = 0.f;
    const float2* xfb = (const float2*)(xf + (size_t)b * WC * NKC);
    #pragma unroll 4
    for (int i = 0; i < WC; ++i) {
        float2 cs = xfb[i * NM + k];
        float wrv = wr[(i * WC + o) * NM + k];
        float wiv = wi[(i * WC + o) * NM + k];
        orr = fmaf(cs.x, wrv, fmaf(cs.y, wiv, orr));    // xfr*wr - xfi*wi
        oii = fmaf(cs.x, wiv, fmaf(-cs.y, wrv, oii));   // xfr*wi + xfi*wr
    }
    float alpha = (k == 0 ? 1.f : 2.f) / (float)SB;
    float2 res = make_float2(alpha * orr, -alpha * oii);
    ((float2*)of)[(size_t)(b * WC + o) * NM + k] = res;
}

// fused inverse-DFT + pointwise conv + bias + relu, in-place on h2[b][s][ch].
// 2-column register blocking; dense float4 VMEM per column.
__global__ __launch_bounds__(256) void k_update(float* __restrict__ h2,
                                                const float* __restrict__ T,
                                                const float* __restrict__ of,
                                                const float* __restrict__ pw,
                                                const float* __restrict__ pwb,
                                                int relu) {
    __shared__ float At[96][64];   // 24 KB; At[k][o]
    int b = blockIdx.y;
    int s0 = blockIdx.x * 512 + threadIdx.x;   // second column: s0 + 256

    const float* ofb = of + (size_t)b * WC * NKC;
    for (int e = threadIdx.x; e < 96 * 64; e += 256) {
        int k = e >> 6, o = e & 63;
        At[k][o] = (k < 64) ? pw[o * 64 + k] : ofb[o * 32 + (k - 64)];
    }

    float* h0p = h2 + ((size_t)b * SB + s0) * WC;
    float* h1p = h0p + 256 * WC;
    float acc0[64], acc1[64];
    #pragma unroll
    for (int o = 0; o < 64; ++o) { acc0[o] = pwb[o]; acc1[o] = pwb[o]; }
    __syncthreads();

    // pointwise part: K = 64, chunks of 8 (2 float4 loads per column per chunk)
    for (int kc = 0; kc < 8; ++kc) {
        float4 a0 = ((const float4*)h0p)[kc * 2];
        float4 b0 = ((const float4*)h0p)[kc * 2 + 1];
        float4 a1 = ((const float4*)h1p)[kc * 2];
        float4 b1 = ((const float4*)h1p)[kc * 2 + 1];
        float xs0[8] = {a0.x, a0.y, a0.z, a0.w, b0.x, b0.y, b0.z, b0.w};
        float xs1[8] = {a1.x, a1.y, a1.z, a1.w, b1.x, b1.y, b1.z, b1.w};
        #pragma unroll
        for (int u = 0; u < 8; ++u) {
            const float4* arow = (const float4*)At[kc * 8 + u];
            #pragma unroll
            for (int o4 = 0; o4 < 16; ++o4) {
                float4 a = arow[o4];
                acc0[o4*4+0] = fmaf(a.x, xs0[u], acc0[o4*4+0]);
                acc0[o4*4+1] = fmaf(a.y, xs0[u], acc0[o4*4+1]);
                acc0[o4*4+2] = fmaf(a.z, xs0[u], acc0[o4*4+2]);
                acc0[o4*4+3] = fmaf(a.w, xs0[u], acc0[o4*4+3]);
                acc1[o4*4+0] = fmaf(a.x, xs1[u], acc1[o4*4+0]);
                acc1[o4*4+1] = fmaf(a.y, xs1[u], acc1[o4*4+1]);
                acc1[o4*4+2] = fmaf(a.z, xs1[u], acc1[o4*4+2]);
                acc1[o4*4+3] = fmaf(a.w, xs1[u], acc1[o4*4+3]);
            }
        }
    }
    // inverse-DFT part: K = 32, chunks of 8
    const float4* Trow0 = (const float4*)(T + (size_t)s0 * NKC);
    const float4* Trow1 = (const float4*)(T + (size_t)(s0 + 256) * NKC);
    for (int kc = 0; kc < 4; ++kc) {
        float4 v0 = Trow0[kc * 2], v1 = Trow0[kc * 2 + 1];
        float4 w0 = Trow1[kc * 2], w1v = Trow1[kc * 2 + 1];
        float xs0[8] = {v0.x, v0.y, v0.z, v0.w, v1.x, v1.y, v1.z, v1.w};
        float xs1[8] = {w0.x, w0.y, w0.z, w0.w, w1v.x, w1v.y, w1v.z, w1v.w};
        #pragma unroll
        for (int u = 0; u < 8; ++u) {
            const float4* arow = (const float4*)At[64 + kc * 8 + u];
            #pragma unroll
            for (int o4 = 0; o4 < 16; ++o4) {
                float4 a = arow[o4];
                acc0[o4*4+0] = fmaf(a.x, xs0[u], acc0[o4*4+0]);
                acc0[o4*4+1] = fmaf(a.y, xs0[u], acc0[o4*4+1]);
                acc0[o4*4+2] = fmaf(a.z, xs0[u], acc0[o4*4+2]);
                acc0[o4*4+3] = fmaf(a.w, xs0[u], acc0[o4*4+3]);
                acc1[o4*4+0] = fmaf(a.x, xs1[u], acc1[o4*4+0]);
                acc1[o4*4+1] = fmaf(a.y, xs1[u], acc1[o4*4+1]);
                acc1[o4*4+2] = fmaf(a.z, xs1[u], acc1[o4*4+2]);
                acc1[o4*4+3] = fmaf(a.w, xs1[u], acc1[o4*4+3]);
            }
        }
    }

    #pragma unroll
    for (int o4 = 0; o4 < 16; ++o4) {
        float4 v0 = make_float4(acc0[o4*4+0], acc0[o4*4+1], acc0[o4*4+2], acc0[o4*4+3]);
        float4 v1 = make_float4(acc1[o4*4+0], acc1[o4*4+1], acc1[o4*4+2], acc1[o4*4+3]);
        if (relu) {
            v0.x = fmaxf(v0.x, 0.f); v0.y = fmaxf(v0.y, 0.f);
            v0.z = fmaxf(v0.z, 0.f); v0.w = fmaxf(v0.w, 0.f);
            v1.x = fmaxf(v1.x, 0.f); v1.y = fmaxf(v1.y, 0.f);
            v1.z = fmaxf(v1.z, 0.f); v1.w = fmaxf(v1.w, 0.f);
        }
        ((float4*)h0p)[o4] = v0;
        ((float4*)h1p)[o4] = v1;
    }
}

// final (1-col): t = relu(fc1_w @ h[s,:] + fc1_b); tc[p] = sum_c t[c]*icaT[c][p] + ica_b[p]
__global__ __launch_bounds__(256) void k_final(const float* __restrict__ h2,
                                               const float* __restrict__ fc1_w,
                                               const float* __restrict__ fc1_b,
                                               const float* __restrict__ icaT,
                                               const float* __restrict__ ica_b,
                                               float* __restrict__ out,
                                               float* __restrict__ tc) {
    __shared__ float w1[128][64];   // 32 KB
    __shared__ float e1[128][24];   // 12 KB
    __shared__ float b1[128];
    int b = blockIdx.y;
    int s = blockIdx.x * 256 + threadIdx.x;

    for (int e = threadIdx.x; e < 128 * 64; e += 256) ((float*)w1)[e] = fc1_w[e];
    for (int e = threadIdx.x; e < 128 * NP; e += 256) ((float*)e1)[e] = icaT[e];
    if (threadIdx.x < 128) b1[threadIdx.x] = fc1_b[threadIdx.x];

    float hv[64];
    const float4* hrow = (const float4*)(h2 + ((size_t)b * SB + s) * WC);
    #pragma unroll
    for (int i4 = 0; i4 < 16; ++i4) {
        float4 v = hrow[i4];
        hv[i4*4+0] = v.x; hv[i4*4+1] = v.y; hv[i4*4+2] = v.z; hv[i4*4+3] = v.w;
    }

    float acc[NP];
    #pragma unroll
    for (int p = 0; p < NP; ++p) acc[p] = ica_b[p];
    __syncthreads();

    for (int cc = 0; cc < 16; ++cc) {
        float tv8[8];
        #pragma unroll
        for (int u = 0; u < 8; ++u) {
            int c = cc * 8 + u;
            float t = b1[c];
            const float4* wrow = (const float4*)w1[c];
            #pragma unroll
            for (int i4 = 0; i4 < 16; ++i4) {
                float4 wv = wrow[i4];
                t = fmaf(wv.x, hv[i4*4+0],
                    fmaf(wv.y, hv[i4*4+1],
                    fmaf(wv.z, hv[i4*4+2],
                    fmaf(wv.w, hv[i4*4+3], t))));
            }
            tv8[u] = fmaxf(t, 0.f);
        }
        #pragma unroll
        for (int u = 0; u < 8; ++u) {
            const float4* erow = (const float4*)e1[cc * 8 + u];
            #pragma unroll
            for (int p4 = 0; p4 < 6; ++p4) {
                float4 ev = erow[p4];
                acc[p4*4+0] = fmaf(tv8[u], ev.x, acc[p4*4+0]);
                acc[p4*4+1] = fmaf(tv8[u], ev.y, acc[p4*4+1]);
                acc[p4*4+2] = fmaf(tv8[u], ev.z, acc[p4*4+2]);
                acc[p4*4+3] = fmaf(tv8[u], ev.w, acc[p4*4+3]);
            }
        }
    }

    float osum = 0.f;
    #pragma unroll
    for (int p = 0; p < NP; ++p) osum += acc[p];
    size_t idx = (size_t)b * SB + s;
    out[idx] = osum;

    float4* t4 = (float4*)(tc + idx * NP);   // 96B stride; thread covers 96B, wave covers 6KB densely
    t4[0] = make_float4(acc[0],  acc[1],  acc[2],  acc[3]);
    t4[1] = make_float4(acc[4],  acc[5],  acc[6],  acc[7]);
    t4[2] = make_float4(acc[8],  acc[9],  acc[10], acc[11]);
    t4[3] = make_float4(acc[12], acc[13], acc[14], acc[15]);
    t4[4] = make_float4(acc[16], acc[17], acc[18], acc[19]);
    t4[5] = make_float4(acc[20], acc[21], acc[22], acc[23]);
}

extern "C" void kernel_launch(void* const* d_in, const int* in_sizes, int n_in,
                              void* d_out, int out_size, void* d_ws, size_t ws_size,
                              hipStream_t stream) {
    const float* x     = (const float*)d_in[0];
    const float* fc0_w = (const float*)d_in[1];
    const float* fc0_b = (const float*)d_in[2];
    const float* cwr   = (const float*)d_in[3];
    const float* cwi   = (const float*)d_in[4];
    const float* pw_w  = (const float*)d_in[5];
    const float* pw_b  = (const float*)d_in[6];
    const float* fc1_w = (const float*)d_in[7];
    const float* fc1_b = (const float*)d_in[8];
    const float* fc2_w = (const float*)d_in[9];
    const float* ica_w = (const float*)d_in[10];
    const float* ica_b = (const float*)d_in[11];

    float* out = (float*)d_out;            // (B,S,1) = 262144
    float* tc  = out + (size_t)NB * SB;    // (B,S,1,24) = 6291456

    float* ws   = (float*)d_ws;
    float* h2   = ws;
    float* T    = ws + 16777216;
    float* xf   = ws + 17039360;
    float* of   = ws + 17104896;
    float* icaT = ws + 17170432;
    float* xfp  = tc;                      // k_dft partials scratch (dead until k_final)

    k_table<<<32, 256, 0, stream>>>(T);
    k_prep<<<12, 256, 0, stream>>>(ica_w, fc2_w, icaT);
    k_lift<<<dim3(32, 32), 256, 0, stream>>>(x, fc0_w, fc0_b, h2);

    for (int l = 0; l < 4; ++l) {
        k_dft<<<NB * NSC, 256, 0, stream>>>(h2, T, xfp);
        k_red<<<256, 256, 0, stream>>>(xfp, xf);
        k_mix<<<128, 256, 0, stream>>>(xf, cwr + (size_t)l * WC * WC * NM,
                                       cwi + (size_t)l * WC * WC * NM, of);
        k_update<<<dim3(16, 32), 256, 0, stream>>>(h2, T, of,
                                                   pw_w + (size_t)l * WC * WC,
                                                   pw_b + (size_t)l * WC,
                                                   (l < 3) ? 1 : 0);
    }

    k_final<<<dim3(32, 32), 256, 0, stream>>>(h2, fc1_w, fc1_b, icaT, ica_b, out, tc);
}